// Round 6
// baseline (408.760 us; speedup 1.0000x reference)
//
#include <hip/hip_runtime.h>
#include <hip/hip_bf16.h>

#define LL 4
#define NN 50000
#define DD 64
#define EE 500000
#define HID 256
#define KDIM 512
#define LN_EPS 1e-5f

typedef __bf16 bf16x8 __attribute__((ext_vector_type(8)));
typedef float f32x16 __attribute__((ext_vector_type(16)));

__device__ __forceinline__ void async16(const void* g, void* l) {
    __builtin_amdgcn_global_load_lds(
        (const __attribute__((address_space(1))) void*)g,
        (__attribute__((address_space(3))) void*)l, 16, 0, 0);
}

// ---------- kernel 1: t[l,n,d] = bf16( tanh( imp_l * h[l,n,d] ) ) ----------
__global__ void tanh_conv(const float* __restrict__ h, __bf16* __restrict__ t) {
    int i = (blockIdx.x * 256 + threadIdx.x) * 8;          // 12.8M elems, 8/thread
    int l = i / (NN * DD);
    float imp = (float)(l + 1) * 0.1f;
    const float4* p = (const float4*)(h + i);
    float4 a = p[0];
    float4 b = p[1];
    float x[8] = {a.x, a.y, a.z, a.w, b.x, b.y, b.z, b.w};
    bf16x8 r;
    #pragma unroll
    for (int j = 0; j < 8; ++j) {
        float e2 = __expf(2.0f * (imp * x[j]));
        r[j] = (__bf16)(1.0f - 2.0f / (e2 + 1.0f));
    }
    *(bf16x8*)(t + i) = r;
}

// ---------- kernel 2: W1 (256x512 f32) -> bf16, layout [kc][q][h][8] ----------
// element (h, k) with k = kc*32 + q*8 + j  ->  w1c[((kc*4+q)*256 + h)*8 + j]
// equivalently: elem offset = (2*(k/16) + (k%16)/8)*2048 + h*8 + k%8
__global__ void w1_conv(const float* __restrict__ w1, __bf16* __restrict__ o) {
    int t = blockIdx.x * 256 + threadIdx.x;                 // 4096 threads
    int kc = t >> 8;
    int h  = t & 255;
    const float4* p = (const float4*)(w1 + h * KDIM + kc * 32);
    #pragma unroll
    for (int qq = 0; qq < 4; ++qq) {
        float4 va = p[2 * qq];
        float4 vb = p[2 * qq + 1];
        bf16x8 r;
        r[0] = (__bf16)va.x; r[1] = (__bf16)va.y; r[2] = (__bf16)va.z; r[3] = (__bf16)va.w;
        r[4] = (__bf16)vb.x; r[5] = (__bf16)vb.y; r[6] = (__bf16)vb.z; r[7] = (__bf16)vb.w;
        *(bf16x8*)(o + ((size_t)(kc * 4 + qq) * 256 + h) * 8) = r;
    }
}

// ---------- epilogue macro for one 32x32 m-tile set (4 nt tiles) ----------
// 32x32x16 C/D layout: col = lane&31 (c32), row = (r&3) + 8*(r>>2) + 4*h32.
// Macro so no pointer to acc arrays is formed (R2 lesson: pointer -> scratch).
#define EPI(ACC, MT)                                                          \
    do {                                                                      \
        float sum[16], sq[16];                                                \
        _Pragma("unroll")                                                     \
        for (int r = 0; r < 16; ++r) { sum[r] = 0.f; sq[r] = 0.f; }           \
        _Pragma("unroll")                                                     \
        for (int nt = 0; nt < 4; ++nt) {                                      \
            _Pragma("unroll")                                                 \
            for (int r = 0; r < 16; ++r) {                                    \
                float v = ACC[nt][r] + b1v[nt];                               \
                sum[r] += v;                                                  \
                sq[r]   = fmaf(v, v, sq[r]);                                  \
            }                                                                 \
        }                                                                     \
        _Pragma("unroll")                                                     \
        for (int m = 1; m < 32; m <<= 1) {                                    \
            _Pragma("unroll")                                                 \
            for (int r = 0; r < 16; ++r) {                                    \
                sum[r] += __shfl_xor(sum[r], m);                              \
                sq[r]  += __shfl_xor(sq[r],  m);                              \
            }                                                                 \
        }                                                                     \
        if (c32 == 0) {                                                       \
            _Pragma("unroll")                                                 \
            for (int r = 0; r < 16; ++r) {                                    \
                exs[wave][MT][h32][r] = sum[r];                               \
                exq[wave][MT][h32][r] = sq[r];                                \
            }                                                                 \
        }                                                                     \
        __syncthreads();                                                      \
        float mu[16], rs[16];                                                 \
        _Pragma("unroll")                                                     \
        for (int r = 0; r < 16; ++r) {                                        \
            float s = sum[r] + exs[wave ^ 1][MT][h32][r];                     \
            float t2 = sq[r] + exq[wave ^ 1][MT][h32][r];                     \
            mu[r] = s * (1.0f / 256.0f);                                      \
            rs[r] = rsqrtf(t2 * (1.0f / 256.0f) - mu[r] * mu[r] + LN_EPS);    \
        }                                                                     \
        float dot[16];                                                        \
        _Pragma("unroll")                                                     \
        for (int r = 0; r < 16; ++r) dot[r] = 0.f;                            \
        _Pragma("unroll")                                                     \
        for (int nt = 0; nt < 4; ++nt) {                                      \
            _Pragma("unroll")                                                 \
            for (int r = 0; r < 16; ++r) {                                    \
                float v = ACC[nt][r] + b1v[nt];                               \
                float y = fmaxf((v - mu[r]) * rs[r] * gv[nt] + btv[nt], 0.f); \
                dot[r] = fmaf(y, wv[nt], dot[r]);                             \
            }                                                                 \
        }                                                                     \
        _Pragma("unroll")                                                     \
        for (int m = 1; m < 32; m <<= 1) {                                    \
            _Pragma("unroll")                                                 \
            for (int r = 0; r < 16; ++r) dot[r] += __shfl_xor(dot[r], m);     \
        }                                                                     \
        if (c32 == 0) {                                                       \
            _Pragma("unroll")                                                 \
            for (int r = 0; r < 16; ++r) exd[wave][MT][h32][r] = dot[r];      \
        }                                                                     \
        __syncthreads();                                                      \
        if (hw == 0 && c32 == 0) {                                            \
            float b3v = b3[0];                                                \
            _Pragma("unroll")                                                 \
            for (int r = 0; r < 16; ++r) {                                    \
                int e = e_base + (MT) * 32 + (r & 3) + 8 * (r >> 2) + 4 * h32;\
                if (e < EE)                                                   \
                    out[e] = dot[r] + exd[wave + 1][MT][h32][r] + b3v;        \
            }                                                                 \
        }                                                                     \
    } while (0)

// ---------- kernel 3: gather + GEMM + LN + ReLU + dot ----------
// WG = 256 threads (4 waves), 128 edges/WG. Wave pair ep = wave>>1 owns 64
// edges (2 m-tiles of 32, MFMA 32x32x16); hw = wave&1 picks 128 of 256 hid
// (4 nt tiles). acc = 8 x f32x16 = 128 regs.
// K-loop: 8 stages of K=64 (32 KB B, double-buffered, 71 KB LDS total).
// ALL VMEM (B-DMA for s+1 + batched A-frag regs for s+1) issues at stage
// START; the stage's ~2000 cyc of MFMA ages the loads so the barrier's
// vmcnt(0) drain is ~free (R4/R5 lost ~700 cyc/barrier to fresh loads).
// Stage s = one (layer, half) plane: per m-tile the 4 A pieces are one
// 128 B node row -> L2-friendly.
__global__ __launch_bounds__(256, 2)
void edge_mlp(const __bf16* __restrict__ tb, const __bf16* __restrict__ w1c,
              const int* __restrict__ src, const int* __restrict__ dst,
              const float* __restrict__ b1, const float* __restrict__ w3,
              const float* __restrict__ b3, const float* __restrict__ gamma,
              const float* __restrict__ beta, float* __restrict__ out) {
    __shared__ __bf16 B_lds[2 * 16384];  // 2 x 32 KB stages
    __shared__ float eb[4 * 256];        // b1 | gamma | beta | w3
    __shared__ float exs[4][2][2][16];   // [wave][mt][h32][r]
    __shared__ float exq[4][2][2][16];
    __shared__ float exd[4][2][2][16];

    const int tid  = threadIdx.x;
    const int wave = tid >> 6;
    const int lane = tid & 63;
    const int h32  = lane >> 5;
    const int c32  = lane & 31;
    const int ep   = wave >> 1;   // 64-edge group
    const int hw   = wave & 1;    // 128-hid half

    eb[tid]       = b1[tid];
    eb[256 + tid] = gamma[tid];
    eb[512 + tid] = beta[tid];
    eb[768 + tid] = w3[tid];

    const int e_base = blockIdx.x * 128 + ep * 64;
    const int e0 = e_base + c32;
    const int e1 = e_base + 32 + c32;
    const int os0 = ((e0 < EE) ? src[e0] : 0) * DD;
    const int od0 = ((e0 < EE) ? dst[e0] : 0) * DD;
    const int os1 = ((e1 < EE) ? src[e1] : 0) * DD;
    const int od1 = ((e1 < EE) ? dst[e1] : 0) * DD;

    // DMA stage 0 (32 KB linear, 8 x 16B per thread)
    #pragma unroll
    for (int j = 0; j < 8; ++j)
        async16(w1c + (j * 256 + tid) * 8, &B_lds[(j * 256 + tid) * 8]);

    // batched A for stage 0 (layer 0, src): 4 x 16B pieces of each node row
    // A-frag for k-step u: m = c32, k = u*16 + h32*8 + j  ->  d = u*16 + h32*8
    uint4 ac0[4], ac1[4];
    #pragma unroll
    for (int j = 0; j < 4; ++j) {
        const __bf16* p = tb + j * 16 + h32 * 8;
        ac0[j] = *(const uint4*)(p + os0);
        ac1[j] = *(const uint4*)(p + os1);
    }

    f32x16 acc0[4], acc1[4];
    #pragma unroll
    for (int i = 0; i < 4; ++i) {
        acc0[i] = (f32x16)(0.f);
        acc1[i] = (f32x16)(0.f);
    }

    __syncthreads();   // stage 0 + eb ready

    int buf = 0;
    for (int s = 0; s < 8; ++s) {
        uint4 an0[4], an1[4];
        if (s < 7) {
            // ALL issue up-front: B-DMA for s+1, then batched A for s+1
            const int sn = s + 1;
            const __bf16* sw = w1c + sn * 16384;
            __bf16* dl = &B_lds[(buf ^ 1) * 16384];
            #pragma unroll
            for (int j = 0; j < 8; ++j)
                async16(sw + (j * 256 + tid) * 8, dl + (j * 256 + tid) * 8);
            const __bf16* plane = tb + (sn >> 1) * (NN * DD) + h32 * 8;
            const int o0 = (sn & 1) ? od0 : os0;
            const int o1 = (sn & 1) ? od1 : os1;
            #pragma unroll
            for (int j = 0; j < 4; ++j) {
                an0[j] = *(const uint4*)(plane + o0 + j * 16);
                an1[j] = *(const uint4*)(plane + o1 + j * 16);
            }
        }
        // compute stage s: 4 k-steps x (2 mt x 4 nt) MFMAs, zero new VMEM
        const __bf16* Bb = &B_lds[buf * 16384 + h32 * 2048 + (hw * 128 + c32) * 8];
        #pragma unroll
        for (int u = 0; u < 4; ++u) {
            bf16x8 af0 = __builtin_bit_cast(bf16x8, ac0[u]);
            bf16x8 af1 = __builtin_bit_cast(bf16x8, ac1[u]);
            const __bf16* Bk = Bb + u * 4096;   // (2u + h32)*2048 + ...
            #pragma unroll
            for (int nt = 0; nt < 4; ++nt) {
                bf16x8 bf = *(const bf16x8*)(Bk + nt * 256);
                acc0[nt] = __builtin_amdgcn_mfma_f32_32x32x16_bf16(af0, bf, acc0[nt], 0, 0, 0);
                acc1[nt] = __builtin_amdgcn_mfma_f32_32x32x16_bf16(af1, bf, acc1[nt], 0, 0, 0);
            }
        }
        __syncthreads();   // loads are ~2000 cyc old -> drain ~free
        if (s < 7) {
            #pragma unroll
            for (int j = 0; j < 4; ++j) { ac0[j] = an0[j]; ac1[j] = an1[j]; }
        }
        buf ^= 1;
    }

    // per-lane epilogue constants for this wave's 4 nt columns
    float b1v[4], gv[4], btv[4], wv[4];
    #pragma unroll
    for (int nt = 0; nt < 4; ++nt) {
        int hh = hw * 128 + nt * 32 + c32;
        b1v[nt] = eb[hh];
        gv[nt]  = eb[256 + hh];
        btv[nt] = eb[512 + hh];
        wv[nt]  = eb[768 + hh];
    }
    EPI(acc0, 0);
    EPI(acc1, 1);
}

extern "C" void kernel_launch(void* const* d_in, const int* in_sizes, int n_in,
                              void* d_out, int out_size, void* d_ws, size_t ws_size,
                              hipStream_t stream) {
    const float* h_all  = (const float*)d_in[0];
    const int*   src    = (const int*)  d_in[1];
    const int*   dst    = (const int*)  d_in[2];
    const float* W1     = (const float*)d_in[3];
    const float* b1     = (const float*)d_in[4];
    const float* W3     = (const float*)d_in[5];
    const float* b3     = (const float*)d_in[6];
    const float* gamma2 = (const float*)d_in[7];
    const float* beta2  = (const float*)d_in[8];
    float* out = (float*)d_out;

    __bf16* tb  = (__bf16*)d_ws;                       // 12.8M bf16 = 25.6 MB
    __bf16* w1c = tb + (size_t)LL * NN * DD;           // 131072 bf16 = 256 KB

    tanh_conv<<<6250, 256, 0, stream>>>(h_all, tb);
    w1_conv<<<16, 256, 0, stream>>>(W1, w1c);
    edge_mlp<<<(EE + 127) / 128, 256, 0, stream>>>(tb, w1c, src, dst,
                                                   b1, W3, b3, gamma2, beta2, out);
}

// Round 7
// 202.620 us; speedup vs baseline: 2.0174x; 2.0174x over previous
//
#include <hip/hip_runtime.h>
#include <hip/hip_bf16.h>

#define LL 4
#define NN 50000
#define DD 64
#define EE 500000
#define HID 256
#define KDIM 512
#define LN_EPS 1e-5f

typedef __bf16 bf16x8 __attribute__((ext_vector_type(8)));
typedef float f32x16 __attribute__((ext_vector_type(16)));

__device__ __forceinline__ void async16(const void* g, void* l) {
    __builtin_amdgcn_global_load_lds(
        (const __attribute__((address_space(1))) void*)g,
        (__attribute__((address_space(3))) void*)l, 16, 0, 0);
}

// ---------- kernel 1: t[l,n,d] = bf16( tanh( imp_l * h[l,n,d] ) ) ----------
__global__ void tanh_conv(const float* __restrict__ h, __bf16* __restrict__ t) {
    int i = (blockIdx.x * 256 + threadIdx.x) * 8;          // 12.8M elems, 8/thread
    int l = i / (NN * DD);
    float imp = (float)(l + 1) * 0.1f;
    const float4* p = (const float4*)(h + i);
    float4 a = p[0];
    float4 b = p[1];
    float x[8] = {a.x, a.y, a.z, a.w, b.x, b.y, b.z, b.w};
    bf16x8 r;
    #pragma unroll
    for (int j = 0; j < 8; ++j) {
        float e2 = __expf(2.0f * (imp * x[j]));
        r[j] = (__bf16)(1.0f - 2.0f / (e2 + 1.0f));
    }
    *(bf16x8*)(t + i) = r;
}

// ---------- kernel 2: W1 (256x512 f32) -> W'' (512 out-cols x 256 K) bf16 ----
// Out-col j<256: Ps row j (src cols of W1); j>=256: Pd row j-256 (dst cols).
// K index k means feature (l = k>>6, d = k&63) -> W1 col l*128 + 64*(j>=256) + d.
// Chunk layout: w2c[(b*512 + j)*8 + z], b = (k>>4)*2 + ((k>>3)&1), z = k&7.
__global__ void w2_conv(const float* __restrict__ w1, __bf16* __restrict__ o) {
    int t = blockIdx.x * 256 + threadIdx.x;                 // 16384 threads
    int j  = t & 511;
    int b  = t >> 9;              // [0,32)
    int k0 = (b >> 1) * 16 + (b & 1) * 8;
    int r  = j & 255;
    int col = (k0 >> 6) * 128 + ((j >> 8) ? 64 : 0) + (k0 & 63);
    const float4* p = (const float4*)(w1 + r * KDIM + col);
    float4 va = p[0];
    float4 vb = p[1];
    bf16x8 v;
    v[0] = (__bf16)va.x; v[1] = (__bf16)va.y; v[2] = (__bf16)va.z; v[3] = (__bf16)va.w;
    v[4] = (__bf16)vb.x; v[5] = (__bf16)vb.y; v[6] = (__bf16)vb.z; v[7] = (__bf16)vb.w;
    *(bf16x8*)(o + (size_t)t * 8) = v;
}

// ---------- kernel 3: node projections P[n][512] = [Ps | Pd] (bf16) ----------
// Grid (391, 4). WG = 256 thr / 4 waves; tile = 128 nodes x 128 out-cols.
// Wave w: nodes n00 + w*32 (one 32-m-tile) x 128 cols (4 nt tiles); acc = 64 AGPR.
// B slice (128 cols x K=256 = 64 KB) staged ONCE via async DMA -> zero
// barriers in the K-loop. A (16 frags, sequential nodes -> coalesced/L2)
// prefetched entirely into 64 VGPRs before the loop.
__global__ __launch_bounds__(256, 2)
void node_proj(const __bf16* __restrict__ tb, const __bf16* __restrict__ w2c,
               __bf16* __restrict__ P) {
    __shared__ __align__(16) char smem[65536];
    __bf16* Bs = (__bf16*)smem;       // 32768 bf16 during GEMM
    float*  Cs = (float*)smem;        // 16384 f32 during store bounce

    const int tid  = threadIdx.x;
    const int wave = tid >> 6;
    const int lane = tid & 63;
    const int h32  = lane >> 5;
    const int c32  = lane & 31;
    const int cb   = blockIdx.y;      // which 128 of 512 out-cols
    const int n00  = blockIdx.x * 128;

    // stage B slice: 16 x 2KB linear pieces
    #pragma unroll
    for (int it = 0; it < 16; ++it) {
        int o = it * 2048 + tid * 8;   // elem offset within 32768-elem slice
        async16(w2c + (size_t)(o >> 10) * 4096 + cb * 1024 + (o & 1023), Bs + o);
    }

    // prefetch all 16 A-frags (m = c32 -> node, k = u*16 + h32*8 + z)
    int node = n00 + wave * 32 + c32;
    if (node >= NN) node = NN - 1;
    uint4 a[16];
    #pragma unroll
    for (int u = 0; u < 16; ++u) {
        const __bf16* p = tb + (size_t)(u >> 2) * (NN * DD) + node * DD
                        + (u & 3) * 16 + h32 * 8;
        a[u] = *(const uint4*)p;
    }

    f32x16 acc[4];
    #pragma unroll
    for (int nt = 0; nt < 4; ++nt) acc[nt] = (f32x16)(0.f);

    __syncthreads();   // B resident (drain is the staging itself - fine, once)

    #pragma unroll
    for (int u = 0; u < 16; ++u) {
        bf16x8 af = __builtin_bit_cast(bf16x8, a[u]);
        const __bf16* Bk = Bs + (u * 2 + h32) * 1024 + c32 * 8;
        #pragma unroll
        for (int nt = 0; nt < 4; ++nt) {
            bf16x8 bf = *(const bf16x8*)(Bk + nt * 256);
            acc[nt] = __builtin_amdgcn_mfma_f32_32x32x16_bf16(af, bf, acc[nt], 0, 0, 0);
        }
    }
    __syncthreads();   // all waves done reading Bs

    // bounce C through LDS to get coalesced bf16 row stores
    // C/D 32x32 layout: col = c32, row = (r&3) + 8*(r>>2) + 4*h32
    #pragma unroll
    for (int nt = 0; nt < 4; ++nt) {
        #pragma unroll
        for (int r = 0; r < 16; ++r) {
            int nl = wave * 32 + (r & 3) + 8 * (r >> 2) + 4 * h32;
            Cs[nl * 128 + nt * 32 + c32] = acc[nt][r];
        }
    }
    __syncthreads();
    #pragma unroll
    for (int it = 0; it < 8; ++it) {
        int o  = it * 2048 + tid * 8;
        int nl = o >> 7;
        int n  = n00 + nl;
        if (n < NN) {
            bf16x8 v;
            #pragma unroll
            for (int z = 0; z < 8; ++z) v[z] = (__bf16)Cs[o + z];
            *(bf16x8*)(P + (size_t)n * 512 + cb * 128 + (o & 127)) = v;
        }
    }
}

// ---------- kernel 4: per-edge gather + LN + ReLU + dot (no MFMA) ----------
// WG = 256 thr = 16 groups of 16 lanes; group g handles 8 edges (pipelined).
// Lane j of a group covers h = [j*16, j*16+16): reads 32 B of Ps row and
// 32 B of Pd row (512 B/row contiguous -> fully coalesced per group).
__global__ __launch_bounds__(256, 3)
void edge_out(const __bf16* __restrict__ P, const int* __restrict__ src,
              const int* __restrict__ dst, const float* __restrict__ b1,
              const float* __restrict__ w3, const float* __restrict__ b3,
              const float* __restrict__ gamma, const float* __restrict__ beta,
              float* __restrict__ out) {
    const int tid = threadIdx.x;
    const int g   = tid >> 4;
    const int j   = tid & 15;

    // per-lane epilogue constants for h = j*16 .. +16
    float b1v[16], gv[16], btv[16], wv[16];
    {
        const float4* pb = (const float4*)(b1 + j * 16);
        const float4* pg = (const float4*)(gamma + j * 16);
        const float4* pt = (const float4*)(beta + j * 16);
        const float4* pw = (const float4*)(w3 + j * 16);
        #pragma unroll
        for (int z = 0; z < 4; ++z) {
            float4 vb = pb[z], vg = pg[z], vt = pt[z], vw = pw[z];
            b1v[z*4+0] = vb.x; b1v[z*4+1] = vb.y; b1v[z*4+2] = vb.z; b1v[z*4+3] = vb.w;
            gv [z*4+0] = vg.x; gv [z*4+1] = vg.y; gv [z*4+2] = vg.z; gv [z*4+3] = vg.w;
            btv[z*4+0] = vt.x; btv[z*4+1] = vt.y; btv[z*4+2] = vt.z; btv[z*4+3] = vt.w;
            wv [z*4+0] = vw.x; wv [z*4+1] = vw.y; wv [z*4+2] = vw.z; wv [z*4+3] = vw.w;
        }
    }
    const float b3v = b3[0];
    const int e0 = blockIdx.x * 128 + g * 8;

    uint4 cs0, cs1, cd0, cd1, ns0, ns1, nd0, nd1;
    {
        int ec = e0 < EE ? e0 : EE - 1;
        int s = src[ec], d = dst[ec];
        const uint4* ps = (const uint4*)(P + (size_t)s * 512 + j * 16);
        const uint4* pd = (const uint4*)(P + (size_t)d * 512 + 256 + j * 16);
        cs0 = ps[0]; cs1 = ps[1]; cd0 = pd[0]; cd1 = pd[1];
    }
    #pragma unroll
    for (int i = 0; i < 8; ++i) {
        if (i < 7) {
            int e = e0 + i + 1;
            int ec = e < EE ? e : EE - 1;
            int s = src[ec], d = dst[ec];
            const uint4* ps = (const uint4*)(P + (size_t)s * 512 + j * 16);
            const uint4* pd = (const uint4*)(P + (size_t)d * 512 + 256 + j * 16);
            ns0 = ps[0]; ns1 = ps[1]; nd0 = pd[0]; nd1 = pd[1];
        }
        bf16x8 a0 = __builtin_bit_cast(bf16x8, cs0);
        bf16x8 a1 = __builtin_bit_cast(bf16x8, cs1);
        bf16x8 c0 = __builtin_bit_cast(bf16x8, cd0);
        bf16x8 c1 = __builtin_bit_cast(bf16x8, cd1);
        float x[16];
        #pragma unroll
        for (int z = 0; z < 8; ++z) {
            x[z]     = (float)a0[z] + (float)c0[z] + b1v[z];
            x[z + 8] = (float)a1[z] + (float)c1[z] + b1v[z + 8];
        }
        float sum = 0.f, sq = 0.f;
        #pragma unroll
        for (int z = 0; z < 16; ++z) {
            sum += x[z];
            sq   = fmaf(x[z], x[z], sq);
        }
        #pragma unroll
        for (int m = 1; m < 16; m <<= 1) {
            sum += __shfl_xor(sum, m);
            sq  += __shfl_xor(sq,  m);
        }
        float mu = sum * (1.0f / 256.0f);
        float rs = rsqrtf(sq * (1.0f / 256.0f) - mu * mu + LN_EPS);
        float dot = 0.f;
        #pragma unroll
        for (int z = 0; z < 16; ++z) {
            float y = fmaxf((x[z] - mu) * rs * gv[z] + btv[z], 0.f);
            dot = fmaf(y, wv[z], dot);
        }
        #pragma unroll
        for (int m = 1; m < 16; m <<= 1) dot += __shfl_xor(dot, m);
        int e = e0 + i;
        if (j == 0 && e < EE) out[e] = dot + b3v;
        cs0 = ns0; cs1 = ns1; cd0 = nd0; cd1 = nd1;
    }
}

extern "C" void kernel_launch(void* const* d_in, const int* in_sizes, int n_in,
                              void* d_out, int out_size, void* d_ws, size_t ws_size,
                              hipStream_t stream) {
    const float* h_all  = (const float*)d_in[0];
    const int*   src    = (const int*)  d_in[1];
    const int*   dst    = (const int*)  d_in[2];
    const float* W1     = (const float*)d_in[3];
    const float* b1     = (const float*)d_in[4];
    const float* W3     = (const float*)d_in[5];
    const float* b3     = (const float*)d_in[6];
    const float* gamma2 = (const float*)d_in[7];
    const float* beta2  = (const float*)d_in[8];
    float* out = (float*)d_out;

    __bf16* tb  = (__bf16*)d_ws;                       // 12.8M bf16 = 25.6 MB
    __bf16* w2c = tb + (size_t)LL * NN * DD;           // 131072 bf16 = 256 KB
    __bf16* P   = w2c + 131072;                        // 50000*512 bf16 = 51.2 MB

    tanh_conv<<<6250, 256, 0, stream>>>(h_all, tb);
    w2_conv<<<64, 256, 0, stream>>>(W1, w2c);
    node_proj<<<dim3((NN + 127) / 128, 4), 256, 0, stream>>>(tb, w2c, P);
    edge_out<<<(EE + 127) / 128, 256, 0, stream>>>(P, src, dst, b1, W3, b3,
                                                   gamma2, beta2, out);
}